// Round 8
// baseline (14528.387 us; speedup 1.0000x reference)
//
#include <hip/hip_runtime.h>
#include <stdint.h>

typedef unsigned short u16;
typedef unsigned int   u32;
typedef unsigned long long u64;

#define T_STEPS 4096
#define HID     1024
#define KXDIM   512
#define NBLK    256
#define TPB     256
#define NREP    4          // replicas of published h/c pair arrays (reader fan-in / 4)

// ---- LDS byte offsets ----
// gate col c = w*4 + q : gate type q (0=o,1=f,2=i,3=g) of column j = j0 + w
#define WGX_OFF  0         // 16 cols x 512 bf16 (1 KB/col, linear k) = 16 KB
#define WGH_OFF  16384     // 16 cols x 64 chunks x 48B (16 bf16 + pad) = 48 KB
#define WHR_OFF  65536     // 4 cols x 64 chunks x 48B = 12 KB
#define WCR_OFF  77824     // 12 KB
#define HBUF_OFF 90112     // 64 chunks x 80B (16 floats + 16B pad) = 5 KB
#define CBUF_OFF 95232     // 5 KB
#define SMEM_BYTES 100352

// ---- workspace u32 indices ----
#define FLAG_IDX 0        // dtype flag: 0 = bf16 inputs, 1 = f32 inputs
#define GHP_IDX  512                    // NREP replicas x 2048 u32 (1024 pairs each)
#define GCP_IDX  (512 + NREP * 2048)
#define WS_INIT_U32 (512 + 2 * NREP * 2048)

__device__ __forceinline__ float bflo(u32 u){ union{u32 u; float f;} x; x.u = u << 16; return x.f; }
__device__ __forceinline__ float bfhi(u32 u){ union{u32 u; float f;} x; x.u = u & 0xffff0000u; return x.f; }
__device__ __forceinline__ float bfs(u16 v){ union{u32 u; float f;} x; x.u = ((u32)v) << 16; return x.f; }
__device__ __forceinline__ float asf(u32 u){ union{u32 u; float f;} x; x.u = u; return x.f; }
__device__ __forceinline__ u16 f2b(float f){
  union{float f; u32 u;} x; x.f = f;
  u32 r = x.u + 0x7fffu + ((x.u >> 16) & 1u);
  return (u16)(r >> 16);
}

// ---- MALL-coherent tagged-pair exchange (sc0 sc1 = bypass L1/L2, served at
// the device coherence point). Pair k at base+2k: [0]=value bits, [1]=tag.
// 8B store is naturally atomic: payload is its own ready-flag.

__device__ __forceinline__ void st_pair(u32* base, int k, float val, u32 tag){
  union{float f; u32 u;} x; x.f = val;
  u64 d = ((u64)tag << 32) | (u64)x.u;
  asm volatile("global_store_dwordx2 %0, %1, off sc0 sc1"
               :: "v"(base + 2 * k), "v"(d) : "memory");
}

// poll 4 consecutive pairs until all tags == exp; tight loop, late backoff.
// NOTE: s_waitcnt lives in the SAME asm that defines the outputs — the only
// scheme the backend supports (vector types are outputs-only in inline asm;
// tied/input vector constraints do not compile on gfx950).
__device__ __forceinline__ void poll4(const u32* base, int k0, u32 exp, float* v){
  const u32* p0 = base + 2 * k0;
  const u32* p1 = p0 + 4;
  uint4 a0, a1;
  int tries = 0;
  for (;;){
    asm volatile("global_load_dwordx4 %0, %2, off sc0 sc1\n\t"
                 "global_load_dwordx4 %1, %3, off sc0 sc1\n\t"
                 "s_waitcnt vmcnt(0)"
                 : "=&v"(a0), "=&v"(a1) : "v"(p0), "v"(p1) : "memory");
    if (a0.y == exp && a0.w == exp && a1.y == exp && a1.w == exp) break;
    if (++tries > 48) __builtin_amdgcn_s_sleep(8);
  }
  v[0] = asf(a0.x); v[1] = asf(a0.z); v[2] = asf(a1.x); v[3] = asf(a1.z);
}

// dot of 16 fp32 values (in regs) with 16 bf16 weights (8 packed u32 from LDS)
__device__ __forceinline__ float dot16r(const float* hv, const u32* wp, float init){
  u32 uu[8];
  *(uint4*)(uu + 0) = *(const uint4*)(wp + 0);
  *(uint4*)(uu + 4) = *(const uint4*)(wp + 4);
  float s = init;
#pragma unroll
  for (int p = 0; p < 8; ++p){
    s = fmaf(hv[2*p],     bflo(uu[p]), s);
    s = fmaf(hv[2*p + 1], bfhi(uu[p]), s);
  }
  return s;
}

// dot of 16 fp32 activations (padded-chunk layout in LDS) with 16 bf16 weights
__device__ __forceinline__ float dot16(const float* av, const u32* wp){
  float hv[16];
  *(float4*)(hv + 0)  = *(const float4*)(av + 0);
  *(float4*)(hv + 4)  = *(const float4*)(av + 4);
  *(float4*)(hv + 8)  = *(const float4*)(av + 8);
  *(float4*)(hv + 12) = *(const float4*)(av + 12);
  return dot16r(hv, wp, 0.f);
}

// weight fetch: f32 mode rounds (RNE) to bf16; bf16 mode passes through
__device__ __forceinline__ u16 ldw(const void* base, size_t idx, int f32m){
  return f32m ? f2b(((const float*)base)[idx]) : ((const u16*)base)[idx];
}

__global__ void __launch_bounds__(TPB) lstm_init(u32* ws){
  int i = blockIdx.x * blockDim.x + threadIdx.x;
  if (i < WS_INIT_U32) ws[i] = 0u;   // zero flag + replica pair arrays (val=0, tag=0)
}

// dtype sniff: bf16 weights (|w| <= 2^-5) can never have a low-u16 bf16
// exponent field >= 144; f32 mantissa bits hit it with p~0.44 per sample.
__global__ void lstm_detect(const u32* __restrict__ wxg, u32* __restrict__ ws){
  if (threadIdx.x == 0 && blockIdx.x == 0){
    u32 f32m = 0;
    for (int i = 0; i < 128; ++i){
      u32 lo = wxg[i] & 0xffffu;
      u32 ef = (lo >> 7) & 0xffu;
      if (ef >= 144u) f32m = 1u;
    }
    ws[FLAG_IDX] = f32m;
  }
}

__global__ void __launch_bounds__(TPB) lstm_persist(
    const void* __restrict__ x,   const void* __restrict__ Wxg,
    const void* __restrict__ Whg, const void* __restrict__ bg,
    const void* __restrict__ Wcr, const void* __restrict__ Whr,
    const void* __restrict__ br,  void* __restrict__ out,
    u32* __restrict__ ws)
{
  extern __shared__ char smem[];
  const int tid  = threadIdx.x;
  const int b    = blockIdx.x;
  const int j0   = b * 4;            // this block owns h/c indices j0..j0+3
  const int w    = tid >> 6;         // wave id 0..3 ; wave w owns j = j0+w
  const int lane = tid & 63;

  const int f32m = (int)ws[FLAG_IDX];

  u32* ghp = ws + GHP_IDX;           // + r*2048 per replica
  u32* gcp = ws + GCP_IDX;
  u32* ghp_rd = ghp + (b & (NREP - 1)) * 2048;
  u32* gcp_rd = gcp + (b & (NREP - 1)) * 2048;

  u16*   wgx  = (u16*)(smem + WGX_OFF);
  u16*   wgh  = (u16*)(smem + WGH_OFF);
  u16*   whr  = (u16*)(smem + WHR_OFF);
  u16*   wcr  = (u16*)(smem + WCR_OFF);
  float* hbuf = (float*)(smem + HBUF_OFF);
  float* cbuf = (float*)(smem + CBUF_OFF);

  // ---------- one-time weight staging into LDS ----------
  {
    // gate columns: col c = w*4 + q -> type q (o,f,i,g) of column j0 + w
    int c = tid >> 4, sub = tid & 15;
    int ty = c & 3, jl = c >> 2;
    size_t gcol = (size_t)(ty * HID + j0 + jl);
    u16* dx = wgx + c * 512;           // x-rows, linear k (lane l reads k=8l..8l+7)
    for (int k = sub * 32; k < sub * 32 + 32; ++k)
      dx[k] = ldw(Wxg, (size_t)k * 4096 + gcol, f32m);
    u16* dh = wgh + c * 1536;          // h-rows, 48B chunks (lane l: k=16l..16l+15)
    for (int k = sub * 64; k < sub * 64 + 64; ++k)
      dh[(k >> 4) * 24 + (k & 15)] = ldw(Whg, (size_t)k * 4096 + gcol, f32m);
  }
  {
    // W_hr / W_cr columns, padded-chunk layout (24 u16 per 16 used)
    int jl = tid >> 6, sub = tid & 63;
    size_t j = (size_t)(j0 + jl);
    u16* dH = whr + jl * 1536 + sub * 24;
    u16* dC = wcr + jl * 1536 + sub * 24;
    for (int p = 0; p < 16; ++p){
      size_t k = (size_t)(sub * 16 + p);
      dH[p] = ldw(Whr, k * HID + j, f32m);
      dC[p] = ldw(Wcr, k * HID + j, f32m);
    }
  }
  // per-lane register constants: bg for (ty = lane&3, j = j0+w), br[j0+w]
  float bgv, brv;
  {
    size_t bidx = (size_t)((lane & 3) * HID + j0 + w);
    size_t ridx = (size_t)(j0 + w);
    bgv = f32m ? ((const float*)bg)[bidx] : bfs(((const u16*)bg)[bidx]);
    brv = f32m ? ((const float*)br)[ridx] : bfs(((const u16*)br)[ridx]);
  }
  float c_old = 0.0f;                // c state for j = j0+w (lane-replicated)
  __syncthreads();

  for (int t = 0; t < T_STEPS; ++t){
    // ---------- x_t into registers (same addrs all waves -> L2 broadcast) ----------
    float xv[8];
    if (f32m){
      const float* xp = (const float*)x + (size_t)t * KXDIM + lane * 8;
      *(float4*)(xv + 0) = *(const float4*)(xp + 0);
      *(float4*)(xv + 4) = *(const float4*)(xp + 4);
    } else {
      const u16* xp = (const u16*)x + (size_t)t * KXDIM + lane * 8;
      uint4 xr = *(const uint4*)xp;
      xv[0] = bflo(xr.x); xv[1] = bfhi(xr.x);
      xv[2] = bflo(xr.y); xv[3] = bfhi(xr.y);
      xv[4] = bflo(xr.z); xv[5] = bfhi(xr.z);
      xv[6] = bflo(xr.w); xv[7] = bfhi(xr.w);
    }
    // ---------- x-part of the gate dots — computed in the h-poll shadow ----------
    float xacc[4];
#pragma unroll
    for (int q = 0; q < 4; ++q){
      const u32* wp = (const u32*)(wgx + (4 * w + q) * 512) + lane * 4;
      uint4 uu = *(const uint4*)wp;
      float s = 0.f;
      s = fmaf(xv[0], bflo(uu.x), s); s = fmaf(xv[1], bfhi(uu.x), s);
      s = fmaf(xv[2], bflo(uu.y), s); s = fmaf(xv[3], bfhi(uu.y), s);
      s = fmaf(xv[4], bflo(uu.z), s); s = fmaf(xv[5], bfhi(uu.z), s);
      s = fmaf(xv[6], bflo(uu.w), s); s = fmaf(xv[7], bfhi(uu.w), s);
      xacc[q] = s;
    }
    // pin: force xacc materialization BEFORE the poll (scalar float "+v" is
    // legal inline-asm on gfx950; vector-typed pins are not)
    asm volatile("" : "+v"(xacc[0]), "+v"(xacc[1]), "+v"(xacc[2]), "+v"(xacc[3]));

    // ---------- h exchange: poll tagged pairs (tag == t), stage hbuf ----------
    {
      int k = tid * 4;                       // 0..1020
      float hv[4];
      poll4(ghp_rd, k, (u32)t, hv);
      float* hb = hbuf + (k >> 4) * 20 + (k & 15);
      hb[0] = hv[0]; hb[1] = hv[1]; hb[2] = hv[2]; hb[3] = hv[3];
    }
    __syncthreads();                         // barrier 1: hbuf staged

    // ---------- gates: h-part dots + fold; wave w owns j = j0+w ----------
    float gact;
    {
      float hv16[16];
      const float* hp = hbuf + lane * 20;
      *(float4*)(hv16 + 0)  = *(const float4*)(hp + 0);
      *(float4*)(hv16 + 4)  = *(const float4*)(hp + 4);
      *(float4*)(hv16 + 8)  = *(const float4*)(hp + 8);
      *(float4*)(hv16 + 12) = *(const float4*)(hp + 12);
      float acc[4];
#pragma unroll
      for (int q = 0; q < 4; ++q){
        const u32* wp = (const u32*)(wgh + (4 * w + q) * 1536 + lane * 24);
        acc[q] = dot16r(hv16, wp, xacc[q]);
      }
      // folded reduction: lane class (lane&3)==q ends with full sum of acc[q]
#pragma unroll
      for (int q = 0; q < 4; ++q){
        acc[q] += __shfl_xor(acc[q], 1, 64);
        acc[q] += __shfl_xor(acc[q], 2, 64);
      }
      float sel = (lane & 2) ? ((lane & 1) ? acc[3] : acc[2])
                             : ((lane & 1) ? acc[1] : acc[0]);
#pragma unroll
      for (int m = 4; m <= 32; m <<= 1) sel += __shfl_xor(sel, m, 64);
      // activation: ty<3 sigmoid, ty==3 tanh via 2*sig(2g)-1
      int ty = lane & 3;
      float gv = sel + bgv;
      float sarg = (ty == 3) ? 2.0f * gv : gv;
      float sg = 1.0f / (1.0f + __expf(-sarg));
      gact = (ty == 3) ? 2.0f * sg - 1.0f : sg;
    }
    // assemble o,f,i,g from quad; update register c-state; publish c IMMEDIATELY
    int gbase = lane & ~3;
    float ov = __shfl(gact, gbase + 0, 64);
    float fv = __shfl(gact, gbase + 1, 64);
    float iv = __shfl(gact, gbase + 2, 64);
    float gg = __shfl(gact, gbase + 3, 64);
    float cn = fmaf(fv, c_old, iv * gg);
    c_old = cn;
    if (lane < 4) st_pair(gcp + lane * 2048, j0 + w, cn, (u32)(t + 1));

    // ---------- u = h . W_hr (own j) — overlaps c-store propagation ----------
    float ua = dot16(hbuf + lane * 20, (const u32*)(whr + w * 1536 + lane * 24));
#pragma unroll
    for (int m = 1; m <= 32; m <<= 1) ua += __shfl_xor(ua, m, 64);

    // ---------- c exchange: poll tagged pairs (tag == t+1), stage cbuf ----------
    {
      int k = tid * 4;
      float cv[4];
      poll4(gcp_rd, k, (u32)(t + 1), cv);
      float* cb = cbuf + (k >> 4) * 20 + (k & 15);
      cb[0] = cv[0]; cb[1] = cv[1]; cb[2] = cv[2]; cb[3] = cv[3];
    }
    __syncthreads();                         // barrier 2: cbuf staged

    // ---------- stage B: r = u + c_new.W_cr + b_r ; h_new = o*tanh(r) ----------
    {
      float ra = dot16(cbuf + lane * 20, (const u32*)(wcr + w * 1536 + lane * 24));
#pragma unroll
      for (int m = 1; m <= 32; m <<= 1) ra += __shfl_xor(ra, m, 64);
      float r  = ua + ra + brv;              // lane-uniform
      float hn = ov * tanhf(r);
      if (lane < 4) st_pair(ghp + lane * 2048, j0 + w, hn, (u32)(t + 1));
      if (lane == 4){
        if (f32m) ((float*)out)[(size_t)t * HID + j0 + w] = hn;
        else      ((u16*)out)[(size_t)t * HID + j0 + w] = f2b(hn);
      }
    }
    // no trailing barrier needed:
    //  - hbuf rewrite at t+1 happens only after this block's h-poll(t+1)
    //    succeeds, which requires ALL waves of ALL blocks to have finished
    //    stage B(t) (h published at end of stage B) => no hbuf readers left.
    //  - cbuf rewrite at t+1 happens only after barrier 1 of t+1, which every
    //    wave reaches only after finishing stage B(t)'s cbuf reads.
  }
}

extern "C" void kernel_launch(void* const* d_in, const int* in_sizes, int n_in,
                              void* d_out, int out_size, void* d_ws, size_t ws_size,
                              hipStream_t stream)
{
  const void* x   = d_in[0];
  const void* Wxg = d_in[1];
  const void* Whg = d_in[2];
  const void* bg  = d_in[3];
  const void* Wcr = d_in[4];   // NOTE: W_cr precedes W_hr in input order
  const void* Whr = d_in[5];
  const void* br  = d_in[6];
  u32* ws  = (u32*)d_ws;

  (void)in_sizes; (void)n_in; (void)out_size; (void)ws_size;

  lstm_init<<<dim3((WS_INIT_U32 + 255) / 256), dim3(256), 0, stream>>>(ws);
  lstm_detect<<<dim3(1), dim3(64), 0, stream>>>((const u32*)Wxg, ws);

  hipFuncSetAttribute((const void*)lstm_persist,
                      hipFuncAttributeMaxDynamicSharedMemorySize, SMEM_BYTES);
  lstm_persist<<<dim3(NBLK), dim3(TPB), SMEM_BYTES, stream>>>(
      x, Wxg, Whg, bg, Wcr, Whr, br, d_out, ws);
}

// Round 9
// 13976.826 us; speedup vs baseline: 1.0395x; 1.0395x over previous
//
#include <hip/hip_runtime.h>
#include <stdint.h>

typedef unsigned short u16;
typedef unsigned int   u32;
typedef unsigned long long u64;

#define T_STEPS 4096
#define HID     1024
#define KXDIM   512
#define NBLK    256
#define TPB     256
#define NREP    4          // replicas of published h/c pair arrays (reader fan-in / 4)

// ---- LDS byte offsets ----
// gate col c = w*4 + q : gate type q (0=o,1=f,2=i,3=g) of column j = j0 + w
#define WGX_OFF  0         // 16 cols x 512 bf16 (1 KB/col, linear k) = 16 KB
#define WGH_OFF  16384     // 16 cols x 64 chunks x 48B (16 bf16 + pad) = 48 KB
#define WHR_OFF  65536     // 4 cols x 64 chunks x 48B = 12 KB
#define WCR_OFF  77824     // 12 KB
#define HBUF_OFF 90112     // 64 chunks x 80B (16 floats + 16B pad) = 5 KB
#define CBUF_OFF 95232     // 5 KB
#define SMEM_BYTES 100352

// ---- workspace u32 indices ----
#define FLAG_IDX 0        // dtype flag: 0 = bf16 inputs, 1 = f32 inputs
#define GHP_IDX  512                    // NREP replicas x 2048 u32 (1024 pairs each)
#define GCP_IDX  (512 + NREP * 2048)
#define WS_INIT_U32 (512 + 2 * NREP * 2048)

__device__ __forceinline__ float bflo(u32 u){ union{u32 u; float f;} x; x.u = u << 16; return x.f; }
__device__ __forceinline__ float bfhi(u32 u){ union{u32 u; float f;} x; x.u = u & 0xffff0000u; return x.f; }
__device__ __forceinline__ float bfs(u16 v){ union{u32 u; float f;} x; x.u = ((u32)v) << 16; return x.f; }
__device__ __forceinline__ float asf(u32 u){ union{u32 u; float f;} x; x.u = u; return x.f; }
__device__ __forceinline__ u16 f2b(float f){
  union{float f; u32 u;} x; x.f = f;
  u32 r = x.u + 0x7fffu + ((x.u >> 16) & 1u);
  return (u16)(r >> 16);
}

// ---- MALL-coherent tagged-pair exchange. Pair k at base+2k: [0]=value bits,
// [1]=step tag. 8B op is naturally atomic; payload is its own ready-flag.
//
// PUBLISH via global_atomic_swap_x2 (no sc0 -> no return data): an atomic RMW
// executes AT the MALL (device coherence point), bypassing the CU's
// write-combine/store queue that a plain write-through store can linger in.
// Theory: store-visibility latency is the dominant exchange term (~1.0 us of
// the measured ~1.45 us/exchange); the atomic cuts it to ~one-way flight.

__device__ __forceinline__ void st_pair(u32* base, int k, float val, u32 tag){
  union{float f; u32 u;} x; x.f = val;
  u64 d = ((u64)tag << 32) | (u64)x.u;
  asm volatile("global_atomic_swap_x2 %0, %1, off"
               :: "v"(base + 2 * k), "v"(d) : "memory");
}

// poll 4 consecutive pairs until all tags == exp; tight loop, late backoff.
// NOTE: s_waitcnt lives in the SAME asm that defines the outputs — the only
// scheme the backend supports (vector types are outputs-only in inline asm;
// tied/input vector constraints do not compile on gfx950).
__device__ __forceinline__ void poll4(const u32* base, int k0, u32 exp, float* v){
  const u32* p0 = base + 2 * k0;
  const u32* p1 = p0 + 4;
  uint4 a0, a1;
  int tries = 0;
  for (;;){
    asm volatile("global_load_dwordx4 %0, %2, off sc0 sc1\n\t"
                 "global_load_dwordx4 %1, %3, off sc0 sc1\n\t"
                 "s_waitcnt vmcnt(0)"
                 : "=&v"(a0), "=&v"(a1) : "v"(p0), "v"(p1) : "memory");
    if (a0.y == exp && a0.w == exp && a1.y == exp && a1.w == exp) break;
    if (++tries > 48) __builtin_amdgcn_s_sleep(8);
  }
  v[0] = asf(a0.x); v[1] = asf(a0.z); v[2] = asf(a1.x); v[3] = asf(a1.z);
}

// dot of 16 fp32 values (in regs) with 16 bf16 weights (8 packed u32 from LDS)
__device__ __forceinline__ float dot16r(const float* hv, const u32* wp, float init){
  u32 uu[8];
  *(uint4*)(uu + 0) = *(const uint4*)(wp + 0);
  *(uint4*)(uu + 4) = *(const uint4*)(wp + 4);
  float s = init;
#pragma unroll
  for (int p = 0; p < 8; ++p){
    s = fmaf(hv[2*p],     bflo(uu[p]), s);
    s = fmaf(hv[2*p + 1], bfhi(uu[p]), s);
  }
  return s;
}

// dot of 16 fp32 activations (padded-chunk layout in LDS) with 16 bf16 weights
__device__ __forceinline__ float dot16(const float* av, const u32* wp){
  float hv[16];
  *(float4*)(hv + 0)  = *(const float4*)(av + 0);
  *(float4*)(hv + 4)  = *(const float4*)(av + 4);
  *(float4*)(hv + 8)  = *(const float4*)(av + 8);
  *(float4*)(hv + 12) = *(const float4*)(av + 12);
  return dot16r(hv, wp, 0.f);
}

// weight fetch: f32 mode rounds (RNE) to bf16; bf16 mode passes through
__device__ __forceinline__ u16 ldw(const void* base, size_t idx, int f32m){
  return f32m ? f2b(((const float*)base)[idx]) : ((const u16*)base)[idx];
}

__global__ void __launch_bounds__(TPB) lstm_init(u32* ws){
  int i = blockIdx.x * blockDim.x + threadIdx.x;
  if (i < WS_INIT_U32) ws[i] = 0u;   // zero flag + replica pair arrays (val=0, tag=0)
}

// dtype sniff: bf16 weights (|w| <= 2^-5) can never have a low-u16 bf16
// exponent field >= 144; f32 mantissa bits hit it with p~0.44 per sample.
__global__ void lstm_detect(const u32* __restrict__ wxg, u32* __restrict__ ws){
  if (threadIdx.x == 0 && blockIdx.x == 0){
    u32 f32m = 0;
    for (int i = 0; i < 128; ++i){
      u32 lo = wxg[i] & 0xffffu;
      u32 ef = (lo >> 7) & 0xffu;
      if (ef >= 144u) f32m = 1u;
    }
    ws[FLAG_IDX] = f32m;
  }
}

__global__ void __launch_bounds__(TPB) lstm_persist(
    const void* __restrict__ x,   const void* __restrict__ Wxg,
    const void* __restrict__ Whg, const void* __restrict__ bg,
    const void* __restrict__ Wcr, const void* __restrict__ Whr,
    const void* __restrict__ br,  void* __restrict__ out,
    u32* __restrict__ ws)
{
  extern __shared__ char smem[];
  const int tid  = threadIdx.x;
  const int b    = blockIdx.x;
  const int j0   = b * 4;            // this block owns h/c indices j0..j0+3
  const int w    = tid >> 6;         // wave id 0..3 ; wave w owns j = j0+w
  const int lane = tid & 63;

  const int f32m = (int)ws[FLAG_IDX];

  u32* ghp = ws + GHP_IDX;           // + r*2048 per replica
  u32* gcp = ws + GCP_IDX;
  u32* ghp_rd = ghp + (b & (NREP - 1)) * 2048;
  u32* gcp_rd = gcp + (b & (NREP - 1)) * 2048;

  u16*   wgx  = (u16*)(smem + WGX_OFF);
  u16*   wgh  = (u16*)(smem + WGH_OFF);
  u16*   whr  = (u16*)(smem + WHR_OFF);
  u16*   wcr  = (u16*)(smem + WCR_OFF);
  float* hbuf = (float*)(smem + HBUF_OFF);
  float* cbuf = (float*)(smem + CBUF_OFF);

  // ---------- one-time weight staging into LDS ----------
  {
    // gate columns: col c = w*4 + q -> type q (o,f,i,g) of column j0 + w
    int c = tid >> 4, sub = tid & 15;
    int ty = c & 3, jl = c >> 2;
    size_t gcol = (size_t)(ty * HID + j0 + jl);
    u16* dx = wgx + c * 512;           // x-rows, linear k (lane l reads k=8l..8l+7)
    for (int k = sub * 32; k < sub * 32 + 32; ++k)
      dx[k] = ldw(Wxg, (size_t)k * 4096 + gcol, f32m);
    u16* dh = wgh + c * 1536;          // h-rows, 48B chunks (lane l: k=16l..16l+15)
    for (int k = sub * 64; k < sub * 64 + 64; ++k)
      dh[(k >> 4) * 24 + (k & 15)] = ldw(Whg, (size_t)k * 4096 + gcol, f32m);
  }
  {
    // W_hr / W_cr columns, padded-chunk layout (24 u16 per 16 used)
    int jl = tid >> 6, sub = tid & 63;
    size_t j = (size_t)(j0 + jl);
    u16* dH = whr + jl * 1536 + sub * 24;
    u16* dC = wcr + jl * 1536 + sub * 24;
    for (int p = 0; p < 16; ++p){
      size_t k = (size_t)(sub * 16 + p);
      dH[p] = ldw(Whr, k * HID + j, f32m);
      dC[p] = ldw(Wcr, k * HID + j, f32m);
    }
  }
  // per-lane register constants: bg for (ty = lane&3, j = j0+w), br[j0+w]
  float bgv, brv;
  {
    size_t bidx = (size_t)((lane & 3) * HID + j0 + w);
    size_t ridx = (size_t)(j0 + w);
    bgv = f32m ? ((const float*)bg)[bidx] : bfs(((const u16*)bg)[bidx]);
    brv = f32m ? ((const float*)br)[ridx] : bfs(((const u16*)br)[ridx]);
  }
  float c_old = 0.0f;                // c state for j = j0+w (lane-replicated)
  __syncthreads();

  for (int t = 0; t < T_STEPS; ++t){
    // ---------- x_t into registers (same addrs all waves -> L2 broadcast) ----------
    float xv[8];
    if (f32m){
      const float* xp = (const float*)x + (size_t)t * KXDIM + lane * 8;
      *(float4*)(xv + 0) = *(const float4*)(xp + 0);
      *(float4*)(xv + 4) = *(const float4*)(xp + 4);
    } else {
      const u16* xp = (const u16*)x + (size_t)t * KXDIM + lane * 8;
      uint4 xr = *(const uint4*)xp;
      xv[0] = bflo(xr.x); xv[1] = bfhi(xr.x);
      xv[2] = bflo(xr.y); xv[3] = bfhi(xr.y);
      xv[4] = bflo(xr.z); xv[5] = bfhi(xr.z);
      xv[6] = bflo(xr.w); xv[7] = bfhi(xr.w);
    }
    // ---------- x-part of the gate dots — computed in the h-poll shadow ----------
    float xacc[4];
#pragma unroll
    for (int q = 0; q < 4; ++q){
      const u32* wp = (const u32*)(wgx + (4 * w + q) * 512) + lane * 4;
      uint4 uu = *(const uint4*)wp;
      float s = 0.f;
      s = fmaf(xv[0], bflo(uu.x), s); s = fmaf(xv[1], bfhi(uu.x), s);
      s = fmaf(xv[2], bflo(uu.y), s); s = fmaf(xv[3], bfhi(uu.y), s);
      s = fmaf(xv[4], bflo(uu.z), s); s = fmaf(xv[5], bfhi(uu.z), s);
      s = fmaf(xv[6], bflo(uu.w), s); s = fmaf(xv[7], bfhi(uu.w), s);
      xacc[q] = s;
    }
    // pin: force xacc materialization BEFORE the poll (scalar float "+v" is
    // legal inline-asm on gfx950; vector-typed pins are not)
    asm volatile("" : "+v"(xacc[0]), "+v"(xacc[1]), "+v"(xacc[2]), "+v"(xacc[3]));

    // ---------- h exchange: poll tagged pairs (tag == t), stage hbuf ----------
    {
      int k = tid * 4;                       // 0..1020
      float hv[4];
      poll4(ghp_rd, k, (u32)t, hv);
      float* hb = hbuf + (k >> 4) * 20 + (k & 15);
      hb[0] = hv[0]; hb[1] = hv[1]; hb[2] = hv[2]; hb[3] = hv[3];
    }
    __syncthreads();                         // barrier 1: hbuf staged

    // ---------- gates: h-part dots + fold; wave w owns j = j0+w ----------
    float gact;
    {
      float hv16[16];
      const float* hp = hbuf + lane * 20;
      *(float4*)(hv16 + 0)  = *(const float4*)(hp + 0);
      *(float4*)(hv16 + 4)  = *(const float4*)(hp + 4);
      *(float4*)(hv16 + 8)  = *(const float4*)(hp + 8);
      *(float4*)(hv16 + 12) = *(const float4*)(hp + 12);
      float acc[4];
#pragma unroll
      for (int q = 0; q < 4; ++q){
        const u32* wp = (const u32*)(wgh + (4 * w + q) * 1536 + lane * 24);
        acc[q] = dot16r(hv16, wp, xacc[q]);
      }
      // folded reduction: lane class (lane&3)==q ends with full sum of acc[q]
#pragma unroll
      for (int q = 0; q < 4; ++q){
        acc[q] += __shfl_xor(acc[q], 1, 64);
        acc[q] += __shfl_xor(acc[q], 2, 64);
      }
      float sel = (lane & 2) ? ((lane & 1) ? acc[3] : acc[2])
                             : ((lane & 1) ? acc[1] : acc[0]);
#pragma unroll
      for (int m = 4; m <= 32; m <<= 1) sel += __shfl_xor(sel, m, 64);
      // activation: ty<3 sigmoid, ty==3 tanh via 2*sig(2g)-1
      int ty = lane & 3;
      float gv = sel + bgv;
      float sarg = (ty == 3) ? 2.0f * gv : gv;
      float sg = 1.0f / (1.0f + __expf(-sarg));
      gact = (ty == 3) ? 2.0f * sg - 1.0f : sg;
    }
    // assemble o,f,i,g from quad; update register c-state; publish c IMMEDIATELY
    int gbase = lane & ~3;
    float ov = __shfl(gact, gbase + 0, 64);
    float fv = __shfl(gact, gbase + 1, 64);
    float iv = __shfl(gact, gbase + 2, 64);
    float gg = __shfl(gact, gbase + 3, 64);
    float cn = fmaf(fv, c_old, iv * gg);
    c_old = cn;
    if (lane < 4) st_pair(gcp + lane * 2048, j0 + w, cn, (u32)(t + 1));

    // ---------- u = h . W_hr (own j) — overlaps c-publish propagation ----------
    float ua = dot16(hbuf + lane * 20, (const u32*)(whr + w * 1536 + lane * 24));
#pragma unroll
    for (int m = 1; m <= 32; m <<= 1) ua += __shfl_xor(ua, m, 64);

    // ---------- c exchange: poll tagged pairs (tag == t+1), stage cbuf ----------
    {
      int k = tid * 4;
      float cv[4];
      poll4(gcp_rd, k, (u32)(t + 1), cv);
      float* cb = cbuf + (k >> 4) * 20 + (k & 15);
      cb[0] = cv[0]; cb[1] = cv[1]; cb[2] = cv[2]; cb[3] = cv[3];
    }
    __syncthreads();                         // barrier 2: cbuf staged

    // ---------- stage B: r = u + c_new.W_cr + b_r ; h_new = o*tanh(r) ----------
    {
      float ra = dot16(cbuf + lane * 20, (const u32*)(wcr + w * 1536 + lane * 24));
#pragma unroll
      for (int m = 1; m <= 32; m <<= 1) ra += __shfl_xor(ra, m, 64);
      float r  = ua + ra + brv;              // lane-uniform
      float hn = ov * tanhf(r);
      if (lane < 4) st_pair(ghp + lane * 2048, j0 + w, hn, (u32)(t + 1));
      if (lane == 4){
        if (f32m) ((float*)out)[(size_t)t * HID + j0 + w] = hn;
        else      ((u16*)out)[(size_t)t * HID + j0 + w] = f2b(hn);
      }
    }
    // no trailing barrier needed:
    //  - hbuf rewrite at t+1 happens only after this block's h-poll(t+1)
    //    succeeds, which requires ALL waves of ALL blocks to have finished
    //    stage B(t) (h published at end of stage B) => no hbuf readers left.
    //  - cbuf rewrite at t+1 happens only after barrier 1 of t+1, which every
    //    wave reaches only after finishing stage B(t)'s cbuf reads.
  }
}

extern "C" void kernel_launch(void* const* d_in, const int* in_sizes, int n_in,
                              void* d_out, int out_size, void* d_ws, size_t ws_size,
                              hipStream_t stream)
{
  const void* x   = d_in[0];
  const void* Wxg = d_in[1];
  const void* Whg = d_in[2];
  const void* bg  = d_in[3];
  const void* Wcr = d_in[4];   // NOTE: W_cr precedes W_hr in input order
  const void* Whr = d_in[5];
  const void* br  = d_in[6];
  u32* ws  = (u32*)d_ws;

  (void)in_sizes; (void)n_in; (void)out_size; (void)ws_size;

  lstm_init<<<dim3((WS_INIT_U32 + 255) / 256), dim3(256), 0, stream>>>(ws);
  lstm_detect<<<dim3(1), dim3(64), 0, stream>>>((const u32*)Wxg, ws);

  hipFuncSetAttribute((const void*)lstm_persist,
                      hipFuncAttributeMaxDynamicSharedMemorySize, SMEM_BYTES);
  lstm_persist<<<dim3(NBLK), dim3(TPB), SMEM_BYTES, stream>>>(
      x, Wxg, Whg, bg, Wcr, Whr, br, d_out, ws);
}

// Round 10
// 13615.945 us; speedup vs baseline: 1.0670x; 1.0265x over previous
//
#include <hip/hip_runtime.h>
#include <stdint.h>

typedef unsigned short u16;
typedef unsigned int   u32;
typedef unsigned long long u64;

#define T_STEPS 4096
#define HID     1024
#define KXDIM   512
#define NBLK    256
#define TPB     256
#define NREP    4          // replicas of published h/c pair arrays (reader fan-in / 4)

// ---- LDS byte offsets ----
// gate col c = w*4 + q : gate type q (0=o,1=f,2=i,3=g) of column j = j0 + w
#define WGX_OFF  0         // 16 cols x 512 bf16 (1 KB/col, linear k) = 16 KB
#define WGH_OFF  16384     // 16 cols x 64 chunks x 48B (16 bf16 + pad) = 48 KB
#define WHR_OFF  65536     // 4 cols x 64 chunks x 48B = 12 KB
#define WCR_OFF  77824     // 12 KB
#define HBUF_OFF 90112     // 64 chunks x 80B (16 floats + 16B pad) = 5 KB
#define CBUF_OFF 95232     // 5 KB
#define SMEM_BYTES 100352

// ---- workspace u32 indices ----
#define FLAG_IDX 0        // dtype flag: 0 = bf16 inputs, 1 = f32 inputs
#define GHP_IDX  512                    // NREP replicas x 2048 u32 (1024 pairs each)
#define GCP_IDX  (512 + NREP * 2048)
#define WS_INIT_U32 (512 + 2 * NREP * 2048)

__device__ __forceinline__ float bflo(u32 u){ union{u32 u; float f;} x; x.u = u << 16; return x.f; }
__device__ __forceinline__ float bfhi(u32 u){ union{u32 u; float f;} x; x.u = u & 0xffff0000u; return x.f; }
__device__ __forceinline__ float bfs(u16 v){ union{u32 u; float f;} x; x.u = ((u32)v) << 16; return x.f; }
__device__ __forceinline__ float asf(u32 u){ union{u32 u; float f;} x; x.u = u; return x.f; }
__device__ __forceinline__ u16 f2b(float f){
  union{float f; u32 u;} x; x.f = f;
  u32 r = x.u + 0x7fffu + ((x.u >> 16) & 1u);
  return (u16)(r >> 16);
}

// ---- MALL-coherent tagged-pair exchange. Pair k at base+2k: [0]=value bits,
// [1]=step tag. 8B op is naturally atomic; payload is its own ready-flag.
// Publish via global_atomic_swap_x2 (no sc0 -> no return): executes AT the
// MALL, bypassing CU-side store queuing (r9: measured small win over store).

__device__ __forceinline__ void st_pair(u32* base, int k, float val, u32 tag){
  union{float f; u32 u;} x; x.f = val;
  u64 d = ((u64)tag << 32) | (u64)x.u;
  asm volatile("global_atomic_swap_x2 %0, %1, off"
               :: "v"(base + 2 * k), "v"(d) : "memory");
}

// poll 4 consecutive pairs until all tags == exp; tight loop, late backoff.
// NOTE: s_waitcnt lives in the SAME asm that defines the outputs — the only
// scheme the backend supports (vector types are outputs-only in inline asm).
__device__ __forceinline__ void poll4(const u32* base, int k0, u32 exp, float* v){
  const u32* p0 = base + 2 * k0;
  const u32* p1 = p0 + 4;
  uint4 a0, a1;
  int tries = 0;
  for (;;){
    asm volatile("global_load_dwordx4 %0, %2, off sc0 sc1\n\t"
                 "global_load_dwordx4 %1, %3, off sc0 sc1\n\t"
                 "s_waitcnt vmcnt(0)"
                 : "=&v"(a0), "=&v"(a1) : "v"(p0), "v"(p1) : "memory");
    if (a0.y == exp && a0.w == exp && a1.y == exp && a1.w == exp) break;
    if (++tries > 48) __builtin_amdgcn_s_sleep(8);
  }
  v[0] = asf(a0.x); v[1] = asf(a0.z); v[2] = asf(a1.x); v[3] = asf(a1.z);
}

// dot of 16 fp32 values (in regs) with 16 bf16 weights (8 packed u32 from LDS)
__device__ __forceinline__ float dot16r(const float* hv, const u32* wp, float init){
  u32 uu[8];
  *(uint4*)(uu + 0) = *(const uint4*)(wp + 0);
  *(uint4*)(uu + 4) = *(const uint4*)(wp + 4);
  float s = init;
#pragma unroll
  for (int p = 0; p < 8; ++p){
    s = fmaf(hv[2*p],     bflo(uu[p]), s);
    s = fmaf(hv[2*p + 1], bfhi(uu[p]), s);
  }
  return s;
}

// dot of 16 fp32 activations (padded-chunk layout in LDS) with 16 bf16 weights
__device__ __forceinline__ float dot16(const float* av, const u32* wp){
  float hv[16];
  *(float4*)(hv + 0)  = *(const float4*)(av + 0);
  *(float4*)(hv + 4)  = *(const float4*)(av + 4);
  *(float4*)(hv + 8)  = *(const float4*)(av + 8);
  *(float4*)(hv + 12) = *(const float4*)(av + 12);
  return dot16r(hv, wp, 0.f);
}

// x row loader: row t, this lane's 8 elements -> fp32 regs
__device__ __forceinline__ void load_x(float* xv, const void* x, int t, int f32m, int lane){
  if (f32m){
    const float* xp = (const float*)x + (size_t)t * KXDIM + lane * 8;
    *(float4*)(xv + 0) = *(const float4*)(xp + 0);
    *(float4*)(xv + 4) = *(const float4*)(xp + 4);
  } else {
    const u16* xp = (const u16*)x + (size_t)t * KXDIM + lane * 8;
    uint4 xr = *(const uint4*)xp;
    xv[0] = bflo(xr.x); xv[1] = bfhi(xr.x);
    xv[2] = bflo(xr.y); xv[3] = bfhi(xr.y);
    xv[4] = bflo(xr.z); xv[5] = bfhi(xr.z);
    xv[6] = bflo(xr.w); xv[7] = bfhi(xr.w);
  }
}

// weight fetch: f32 mode rounds (RNE) to bf16; bf16 mode passes through
__device__ __forceinline__ u16 ldw(const void* base, size_t idx, int f32m){
  return f32m ? f2b(((const float*)base)[idx]) : ((const u16*)base)[idx];
}

__global__ void __launch_bounds__(TPB) lstm_init(u32* ws){
  int i = blockIdx.x * blockDim.x + threadIdx.x;
  if (i < WS_INIT_U32) ws[i] = 0u;   // zero flag + replica pair arrays (val=0, tag=0)
}

// dtype sniff: bf16 weights (|w| <= 2^-5) can never have a low-u16 bf16
// exponent field >= 144; f32 mantissa bits hit it with p~0.44 per sample.
__global__ void lstm_detect(const u32* __restrict__ wxg, u32* __restrict__ ws){
  if (threadIdx.x == 0 && blockIdx.x == 0){
    u32 f32m = 0;
    for (int i = 0; i < 128; ++i){
      u32 lo = wxg[i] & 0xffffu;
      u32 ef = (lo >> 7) & 0xffu;
      if (ef >= 144u) f32m = 1u;
    }
    ws[FLAG_IDX] = f32m;
  }
}

__global__ void __launch_bounds__(TPB) lstm_persist(
    const void* __restrict__ x,   const void* __restrict__ Wxg,
    const void* __restrict__ Whg, const void* __restrict__ bg,
    const void* __restrict__ Wcr, const void* __restrict__ Whr,
    const void* __restrict__ br,  void* __restrict__ out,
    u32* __restrict__ ws)
{
  extern __shared__ char smem[];
  const int tid  = threadIdx.x;
  const int b    = blockIdx.x;
  const int j0   = b * 4;            // this block owns h/c indices j0..j0+3
  const int w    = tid >> 6;         // wave id 0..3 ; wave w owns j = j0+w
  const int lane = tid & 63;

  const int f32m = (int)ws[FLAG_IDX];

  u32* ghp = ws + GHP_IDX;           // + r*2048 per replica
  u32* gcp = ws + GCP_IDX;
  u32* ghp_rd = ghp + (b & (NREP - 1)) * 2048;
  u32* gcp_rd = gcp + (b & (NREP - 1)) * 2048;

  u16*   wgx  = (u16*)(smem + WGX_OFF);
  u16*   wgh  = (u16*)(smem + WGH_OFF);
  u16*   whr  = (u16*)(smem + WHR_OFF);
  u16*   wcr  = (u16*)(smem + WCR_OFF);
  float* hbuf = (float*)(smem + HBUF_OFF);
  float* cbuf = (float*)(smem + CBUF_OFF);

  // ---------- one-time weight staging into LDS ----------
  {
    // gate columns: col c = w*4 + q -> type q (o,f,i,g) of column j0 + w
    int c = tid >> 4, sub = tid & 15;
    int ty = c & 3, jl = c >> 2;
    size_t gcol = (size_t)(ty * HID + j0 + jl);
    u16* dx = wgx + c * 512;           // x-rows, linear k (lane l reads k=8l..8l+7)
    for (int k = sub * 32; k < sub * 32 + 32; ++k)
      dx[k] = ldw(Wxg, (size_t)k * 4096 + gcol, f32m);
    u16* dh = wgh + c * 1536;          // h-rows, 48B chunks (lane l: k=16l..16l+15)
    for (int k = sub * 64; k < sub * 64 + 64; ++k)
      dh[(k >> 4) * 24 + (k & 15)] = ldw(Whg, (size_t)k * 4096 + gcol, f32m);
  }
  {
    // W_hr / W_cr columns, padded-chunk layout (24 u16 per 16 used)
    int jl = tid >> 6, sub = tid & 63;
    size_t j = (size_t)(j0 + jl);
    u16* dH = whr + jl * 1536 + sub * 24;
    u16* dC = wcr + jl * 1536 + sub * 24;
    for (int p = 0; p < 16; ++p){
      size_t k = (size_t)(sub * 16 + p);
      dH[p] = ldw(Whr, k * HID + j, f32m);
      dC[p] = ldw(Wcr, k * HID + j, f32m);
    }
  }
  // per-lane register constants: bg for (ty = lane&3, j = j0+w), br[j0+w]
  float bgv, brv;
  {
    size_t bidx = (size_t)((lane & 3) * HID + j0 + w);
    size_t ridx = (size_t)(j0 + w);
    bgv = f32m ? ((const float*)bg)[bidx] : bfs(((const u16*)bg)[bidx]);
    brv = f32m ? ((const float*)br)[ridx] : bfs(((const u16*)br)[ridx]);
  }
  float c_old = 0.0f;                // c state for j = j0+w (lane-replicated)

  // ---------- prologue: x row 0 into registers (loop-carried prefetch) ----------
  float xv[8];
  load_x(xv, x, 0, f32m, lane);
  __syncthreads();

  for (int t = 0; t < T_STEPS; ++t){
    // ---------- x-part of the gate dots — LDS+regs only, NO global dependency
    // (x_t was prefetched last iteration), so the h-poll starts immediately ----------
    float xacc[4];
#pragma unroll
    for (int q = 0; q < 4; ++q){
      const u32* wp = (const u32*)(wgx + (4 * w + q) * 512) + lane * 4;
      uint4 uu = *(const uint4*)wp;
      float s = 0.f;
      s = fmaf(xv[0], bflo(uu.x), s); s = fmaf(xv[1], bfhi(uu.x), s);
      s = fmaf(xv[2], bflo(uu.y), s); s = fmaf(xv[3], bfhi(uu.y), s);
      s = fmaf(xv[4], bflo(uu.z), s); s = fmaf(xv[5], bfhi(uu.z), s);
      s = fmaf(xv[6], bflo(uu.w), s); s = fmaf(xv[7], bfhi(uu.w), s);
      xacc[q] = s;
    }
    // pin: force xacc materialization BEFORE the poll
    asm volatile("" : "+v"(xacc[0]), "+v"(xacc[1]), "+v"(xacc[2]), "+v"(xacc[3]));

    // ---------- h exchange: poll tagged pairs (tag == t), stage hbuf ----------
    {
      int k = tid * 4;                       // 0..1020
      float hv[4];
      poll4(ghp_rd, k, (u32)t, hv);
      float* hb = hbuf + (k >> 4) * 20 + (k & 15);
      hb[0] = hv[0]; hb[1] = hv[1]; hb[2] = hv[2]; hb[3] = hv[3];
    }
    __syncthreads();                         // barrier 1: hbuf staged

    // ---------- prefetch x_{t+1}: issued here (fenced between barrier 1 and
    // the c-publish asm); the c-poll's vmcnt(0) drains it ~1 us later — the
    // HBM miss (~0.375 us) is fully hidden off the pre-poll critical path ----------
    float xvn[8];
    {
      int tn = (t + 1 < T_STEPS) ? t + 1 : 0;
      load_x(xvn, x, tn, f32m, lane);
    }

    // ---------- gates: h-part dots + fold; wave w owns j = j0+w ----------
    float gact;
    {
      float hv16[16];
      const float* hp = hbuf + lane * 20;
      *(float4*)(hv16 + 0)  = *(const float4*)(hp + 0);
      *(float4*)(hv16 + 4)  = *(const float4*)(hp + 4);
      *(float4*)(hv16 + 8)  = *(const float4*)(hp + 8);
      *(float4*)(hv16 + 12) = *(const float4*)(hp + 12);
      float acc[4];
#pragma unroll
      for (int q = 0; q < 4; ++q){
        const u32* wp = (const u32*)(wgh + (4 * w + q) * 1536 + lane * 24);
        acc[q] = dot16r(hv16, wp, xacc[q]);
      }
      // folded reduction: lane class (lane&3)==q ends with full sum of acc[q]
#pragma unroll
      for (int q = 0; q < 4; ++q){
        acc[q] += __shfl_xor(acc[q], 1, 64);
        acc[q] += __shfl_xor(acc[q], 2, 64);
      }
      float sel = (lane & 2) ? ((lane & 1) ? acc[3] : acc[2])
                             : ((lane & 1) ? acc[1] : acc[0]);
#pragma unroll
      for (int m = 4; m <= 32; m <<= 1) sel += __shfl_xor(sel, m, 64);
      // activation: ty<3 sigmoid, ty==3 tanh via 2*sig(2g)-1
      int ty = lane & 3;
      float gv = sel + bgv;
      float sarg = (ty == 3) ? 2.0f * gv : gv;
      float sg = 1.0f / (1.0f + __expf(-sarg));
      gact = (ty == 3) ? 2.0f * sg - 1.0f : sg;
    }
    // assemble o,f,i,g from quad; update register c-state; publish c IMMEDIATELY
    int gbase = lane & ~3;
    float ov = __shfl(gact, gbase + 0, 64);
    float fv = __shfl(gact, gbase + 1, 64);
    float iv = __shfl(gact, gbase + 2, 64);
    float gg = __shfl(gact, gbase + 3, 64);
    float cn = fmaf(fv, c_old, iv * gg);
    c_old = cn;
    if (lane < 4) st_pair(gcp + lane * 2048, j0 + w, cn, (u32)(t + 1));

    // ---------- u = h . W_hr (own j) — overlaps c-publish propagation ----------
    float ua = dot16(hbuf + lane * 20, (const u32*)(whr + w * 1536 + lane * 24));
#pragma unroll
    for (int m = 1; m <= 32; m <<= 1) ua += __shfl_xor(ua, m, 64);

    // ---------- c exchange: poll tagged pairs (tag == t+1), stage cbuf ----------
    {
      int k = tid * 4;
      float cv[4];
      poll4(gcp_rd, k, (u32)(t + 1), cv);
      float* cb = cbuf + (k >> 4) * 20 + (k & 15);
      cb[0] = cv[0]; cb[1] = cv[1]; cb[2] = cv[2]; cb[3] = cv[3];
    }
    __syncthreads();                         // barrier 2: cbuf staged

    // ---------- stage B: r = u + c_new.W_cr + b_r ; h_new = o*tanh(r) ----------
    {
      float ra = dot16(cbuf + lane * 20, (const u32*)(wcr + w * 1536 + lane * 24));
#pragma unroll
      for (int m = 1; m <= 32; m <<= 1) ra += __shfl_xor(ra, m, 64);
      float r  = ua + ra + brv;              // lane-uniform
      float hn = ov * tanhf(r);
      if (lane < 4) st_pair(ghp + lane * 2048, j0 + w, hn, (u32)(t + 1));
      if (lane == 4){
        if (f32m) ((float*)out)[(size_t)t * HID + j0 + w] = hn;
        else      ((u16*)out)[(size_t)t * HID + j0 + w] = f2b(hn);
      }
    }
    // carry the prefetched x row into the next iteration
#pragma unroll
    for (int i2 = 0; i2 < 8; ++i2) xv[i2] = xvn[i2];
    // no trailing barrier needed:
    //  - hbuf rewrite at t+1 happens only after this block's h-poll(t+1)
    //    succeeds, which requires ALL waves of ALL blocks to have finished
    //    stage B(t) (h published at end of stage B) => no hbuf readers left.
    //  - cbuf rewrite at t+1 happens only after barrier 1 of t+1, which every
    //    wave reaches only after finishing stage B(t)'s cbuf reads.
  }
}

extern "C" void kernel_launch(void* const* d_in, const int* in_sizes, int n_in,
                              void* d_out, int out_size, void* d_ws, size_t ws_size,
                              hipStream_t stream)
{
  const void* x   = d_in[0];
  const void* Wxg = d_in[1];
  const void* Whg = d_in[2];
  const void* bg  = d_in[3];
  const void* Wcr = d_in[4];   // NOTE: W_cr precedes W_hr in input order
  const void* Whr = d_in[5];
  const void* br  = d_in[6];
  u32* ws  = (u32*)d_ws;

  (void)in_sizes; (void)n_in; (void)out_size; (void)ws_size;

  lstm_init<<<dim3((WS_INIT_U32 + 255) / 256), dim3(256), 0, stream>>>(ws);
  lstm_detect<<<dim3(1), dim3(64), 0, stream>>>((const u32*)Wxg, ws);

  hipFuncSetAttribute((const void*)lstm_persist,
                      hipFuncAttributeMaxDynamicSharedMemorySize, SMEM_BYTES);
  lstm_persist<<<dim3(NBLK), dim3(TPB), SMEM_BYTES, stream>>>(
      x, Wxg, Whg, bg, Wcr, Whr, br, d_out, ws);
}